// Round 14
// baseline (624.036 us; speedup 1.0000x reference)
//
#include <hip/hip_runtime.h>
#include <hip/hip_bf16.h>
#include <stdint.h>

#define N_TOK 8192
#define C_DIM 1024
#define H_DIM 4096
#define E_NUM 5
#define LN_EPS 1e-5f
#define NT_MAX 69              // ceil((8192 + 5*127)/128): padded 128-row M-tiles
#define N_PAD (NT_MAX * 128)   // 8832 padded sorted rows

typedef __hip_bfloat16 bf16;
using s8v = __attribute__((ext_vector_type(8))) short;
using f4v = __attribute__((ext_vector_type(4))) float;

// async global->LDS, 16B per lane. LDS dest must be linear: wave-uniform base + lane*16.
__device__ __forceinline__ void async_ld16(const bf16* g, bf16* l) {
    __builtin_amdgcn_global_load_lds(
        (const __attribute__((address_space(1))) void*)g,
        (__attribute__((address_space(3))) void*)l,
        16, 0, 0);
}

// meta layout (ints): [0..4]=counts, [5..9]=128-aligned offsets, [10]=padded total,
// [11..15]=cursors, [16..16+NT_MAX)=tile->expert table (-1 = empty tile)

// Fused count+scan: one block, LDS histogram, then meta build.
// (R12 lesson: do NOT also fuse scatter — serializing 8192 tokens' ranking
// through one CU costs more than the launch boundary it saves.)
__global__ __launch_bounds__(1024) void count_scan_kernel(
    const int* __restrict__ win, int* __restrict__ meta)
{
    __shared__ int c[E_NUM];
    int t = threadIdx.x;
    if (t < E_NUM) c[t] = 0;
    __syncthreads();
    for (int n = t; n < N_TOK; n += 1024) atomicAdd(&c[win[n]], 1);
    __syncthreads();
    if (t == 0) {
        int off = 0;
        for (int e = 0; e < E_NUM; ++e) {
            meta[e] = c[e];
            meta[5 + e] = off;
            off += (c[e] + 127) & ~127;        // 128-aligned segment
            meta[11 + e] = 0;                  // scatter cursor
        }
        meta[10] = off;
        int ti = 0;
        for (int e = 0; e < E_NUM; ++e) {
            int tiles = (c[e] + 127) >> 7;
            for (int j = 0; j < tiles; ++j) meta[16 + ti++] = e;
        }
        for (; ti < NT_MAX; ++ti) meta[16 + ti] = -1;
    }
}

// Hierarchical scatter (R10 lesson: per-token device-scope atomics on one
// cache line serialize at ~60ns each = 490 µs; LDS local ranks + E_NUM global
// atomics per block = 160 total is ~2 µs).
__global__ __launch_bounds__(256) void scatter_kernel(
    const int* __restrict__ win, int* __restrict__ meta,
    int* __restrict__ idx, int* __restrict__ pos)
{
    __shared__ int c[E_NUM];
    __shared__ int base[E_NUM];
    if (threadIdx.x < E_NUM) c[threadIdx.x] = 0;
    __syncthreads();
    int n = blockIdx.x * 256 + threadIdx.x;
    int e = win[n];
    int lr = atomicAdd(&c[e], 1);
    __syncthreads();
    if (threadIdx.x < E_NUM)
        base[threadIdx.x] = atomicAdd(&meta[11 + threadIdx.x], c[threadIdx.x]);
    __syncthreads();
    int p = meta[5 + e] + base[e] + lr;
    idx[p] = n;
    pos[n] = p;
}

// Shared transpose tile body: src [R][S] fp32 (+ebase) -> dst [S][R] bf16.
// 64x64 tile at (r0, s0); float4 loads; 8 lanes x 16B = one 128B dst line.
__device__ __forceinline__ void transpose_tile(
    const float* __restrict__ src, bf16* __restrict__ dst,
    size_t ebase, int R, int S, int r0, int s0, float (*tile)[65])
{
    int t = threadIdx.x;
    int lr = t >> 4;
    int lc = (t & 15) * 4;
#pragma unroll
    for (int i = 0; i < 4; ++i) {
        int rr = lr + i * 16;
        float4 v = *(const float4*)(src + ebase + (size_t)(r0 + rr) * S + s0 + lc);
        tile[rr][lc + 0] = v.x;
        tile[rr][lc + 1] = v.y;
        tile[rr][lc + 2] = v.z;
        tile[rr][lc + 3] = v.w;
    }
    __syncthreads();
    int ch = t & 7;
    int scb = t >> 3;
#pragma unroll
    for (int p = 0; p < 2; ++p) {
        int sc = scb + p * 32;
        bf16 vals[8];
#pragma unroll
        for (int j = 0; j < 8; ++j)
            vals[j] = (bf16)tile[ch * 8 + j][sc];
        *(s8v*)(dst + ebase + (size_t)(s0 + sc) * R + r0 + ch * 8) = *(s8v*)vals;
    }
}

// Fused: ln_conf (blocks 0..8191) + w1 transpose (blocks 8192..13311).
__global__ __launch_bounds__(256) void ln_conf_w1t_kernel(
    const float* __restrict__ x, const int* __restrict__ win,
    const float* __restrict__ gamma, const float* __restrict__ beta,
    const float* __restrict__ wc, const float* __restrict__ bc,
    const int* __restrict__ pos,
    bf16* __restrict__ hbuf, float* __restrict__ scl,
    const float* __restrict__ w1, bf16* __restrict__ w1t)
{
    __shared__ float tile[64][65];
    if (blockIdx.x >= N_TOK) {
        int r = blockIdx.x - N_TOK;            // [0, 5120)
        int e = r >> 10;
        int cell = r & 1023;
        transpose_tile(w1, w1t, (size_t)e * C_DIM * H_DIM, C_DIM, H_DIM,
                       (cell >> 6) * 64, (cell & 63) * 64, tile);
        return;
    }
    int n = blockIdx.x;
    int t = threadIdx.x;
    const float* xr = x + (size_t)n * C_DIM;
    float v[4];
    float s = 0.f, ss = 0.f;
#pragma unroll
    for (int i = 0; i < 4; ++i) {
        v[i] = xr[t + i * 256];
        s += v[i];
        ss += v[i] * v[i];
    }
#pragma unroll
    for (int off = 32; off > 0; off >>= 1) {
        s  += __shfl_down(s, off);
        ss += __shfl_down(ss, off);
    }
    __shared__ float red[8];
    __shared__ float mu_s, rv_s;
    int wave = t >> 6, lane = t & 63;
    if (lane == 0) { red[wave] = s; red[4 + wave] = ss; }
    __syncthreads();
    if (t == 0) {
        float S  = red[0] + red[1] + red[2] + red[3];
        float SS = red[4] + red[5] + red[6] + red[7];
        float mu = S * (1.f / C_DIM);
        float var = SS * (1.f / C_DIM) - mu * mu;
        mu_s = mu;
        rv_s = rsqrtf(var + LN_EPS);
    }
    __syncthreads();
    float mu = mu_s, rv = rv_s;
    int e = win[n];
    int p = pos[n];
    const float* wce = wc + (size_t)e * C_DIM;
    float dot = 0.f;
#pragma unroll
    for (int i = 0; i < 4; ++i) {
        int ci = t + i * 256;
        float hv = (v[i] - mu) * rv * gamma[ci] + beta[ci];
        hbuf[(size_t)p * C_DIM + ci] = (bf16)hv;
        dot += hv * wce[ci];
    }
#pragma unroll
    for (int off = 32; off > 0; off >>= 1) dot += __shfl_down(dot, off);
    if (lane == 0) red[wave] = dot;
    __syncthreads();
    if (t == 0) {
        float z = red[0] + red[1] + red[2] + red[3] + bc[e];
        float conf = 1.f / (1.f + expf(-z));
        scl[p] = conf / (conf + 1e-6f);
    }
}

// ---------------- GEMM cores -------------------------------------------------
// gemm1: R7-validated config, untouched. gemm2: R14 change = BN 128->256
// (single variable). Tile traffic 1.1 GB -> 828 MB (-25%): B-panel read
// 4x instead of 8x. 276 blocks, 72KB LDS ring -> 2 blocks/CU cap, all
// co-resident. Bijective chunked XCD swizzle (276 % 8 != 0).
// Conflict-free LDS swizzle (R2-validated: conflicts 8.65M -> 0).

// Fused: gemm1 (blocks 0..2207) + w2 transpose (blocks 2208..7327).
__global__ __launch_bounds__(256) void gemm1_w2t_kernel(
    const bf16* __restrict__ hbuf, const bf16* __restrict__ w1t,
    const int* __restrict__ meta, bf16* __restrict__ ks,
    const float* __restrict__ w2, bf16* __restrict__ w2t)
{
    const int GX = H_DIM / 128;            // 32
    const int NWG = GX * NT_MAX;           // 2208 (% 8 == 0)
    if (blockIdx.x >= NWG) {
        __shared__ float tile[64][65];
        int r = blockIdx.x - NWG;              // [0, 5120)
        int e = r >> 10;
        int cell = r & 1023;
        transpose_tile(w2, w2t, (size_t)e * H_DIM * C_DIM, H_DIM, C_DIM,
                       (cell >> 4) * 64, (cell & 15) * 64, tile);
        return;
    }
    int d = blockIdx.x;
    int w = (d & 7) * (NWG >> 3) + (d >> 3);
    int bx = w & (GX - 1);
    int ti = w / GX;
    int e = meta[16 + ti];
    if (e < 0) return;

    int base_p = meta[5 + e];
    int cnt = meta[e];
    int m0 = ti * 128 - base_p;            // local row within expert segment
    int n0 = bx * 128;

    __shared__ __align__(16) bf16 As[128 * 32];
    __shared__ __align__(16) bf16 Bs[128 * 32];

    int t = threadIdx.x;
    int lane = t & 63;
    int wv = t >> 6;
    int wr = wv >> 1, wcol = wv & 1;

    int i0 = (t & 7) ^ ((t >> 3) & 7);
    int srow = 2 * (t >> 3) + (i0 >> 2);
    int schk = i0 & 3;

    int r1 = min(m0 + srow, cnt - 1);
    int r2 = min(m0 + 64 + srow, cnt - 1);
    const bf16* ga1 = hbuf + (size_t)(base_p + r1) * C_DIM + schk * 8;
    const bf16* ga2 = hbuf + (size_t)(base_p + r2) * C_DIM + schk * 8;
    const bf16* wbase = w1t + (size_t)e * H_DIM * C_DIM;
    const bf16* gb1 = wbase + (size_t)(n0 + srow) * C_DIM + schk * 8;
    const bf16* gb2 = wbase + (size_t)(n0 + 64 + srow) * C_DIM + schk * 8;

    bf16* la1 = As + t * 8;
    bf16* la2 = As + 2048 + t * 8;
    bf16* lb1 = Bs + t * 8;
    bf16* lb2 = Bs + 2048 + t * 8;

    int kq = lane >> 4;
    int rhalf = (lane & 15) >> 1;
    int ifrag = ((lane & 1) << 2) | kq;
    int foff = rhalf * 64 + (ifrag ^ rhalf) * 8;
    const bf16* Af = As + wr * 2048 + foff;
    const bf16* Bf = Bs + wcol * 2048 + foff;

    f4v acc[4][4];
    f4v zero = {0.f, 0.f, 0.f, 0.f};
#pragma unroll
    for (int i = 0; i < 4; ++i)
#pragma unroll
        for (int j = 0; j < 4; ++j) acc[i][j] = zero;

    for (int kb = 0; kb < C_DIM / 32; ++kb) {
        __syncthreads();
        async_ld16(ga1, la1); ga1 += 32;
        async_ld16(ga2, la2); ga2 += 32;
        async_ld16(gb1, lb1); gb1 += 32;
        async_ld16(gb2, lb2); gb2 += 32;
        __syncthreads();
        s8v af[4], bfv[4];
#pragma unroll
        for (int mi = 0; mi < 4; ++mi)
            af[mi] = *(const s8v*)(Af + mi * 512);
#pragma unroll
        for (int ni = 0; ni < 4; ++ni)
            bfv[ni] = *(const s8v*)(Bf + ni * 512);
#pragma unroll
        for (int mi = 0; mi < 4; ++mi)
#pragma unroll
            for (int ni = 0; ni < 4; ++ni)
                acc[mi][ni] = __builtin_amdgcn_mfma_f32_16x16x32_bf16(af[mi], bfv[ni], acc[mi][ni], 0, 0, 0);
    }

#pragma unroll
    for (int mi = 0; mi < 4; ++mi) {
#pragma unroll
        for (int r = 0; r < 4; ++r) {
            int row_local = wr * 64 + mi * 16 + ((lane >> 4) << 2) + r;
            int gm = m0 + row_local;
            if (gm < cnt) {
                size_t p = (size_t)(base_p + gm);
#pragma unroll
                for (int ni = 0; ni < 4; ++ni) {
                    int col = n0 + wcol * 64 + ni * 16 + (lane & 15);
                    float v = acc[mi][ni][r];
                    float rl = fmaxf(v, 0.f);
                    ks[p * H_DIM + col] = (bf16)(rl * rl);
                }
            }
        }
    }
}

// Stage 2: out[tok] = x[tok] + (ks[p] @ W2t[e][c])*scl[p]
// BN=256: 128x256 tile per block, 276 blocks. 3-slot depth-2 counted-vmcnt
// ring, 72KB LDS (A 8KB + B 16KB per slot). 6 staging loads/step ->
// steady vmcnt(12), drain 6 -> 0. Waves 2x2: each covers 64 rows x 128 cols
// (acc[4][8]). Bijective XCD chunk swizzle (q=34, r=4).
__global__ __launch_bounds__(256) void gemm2_kernel(
    const bf16* __restrict__ ks, const bf16* __restrict__ w2t,
    const int* __restrict__ idx, const int* __restrict__ meta,
    const float* __restrict__ x, const float* __restrict__ scl,
    float* __restrict__ out)
{
    const int GX = C_DIM / 256;            // 4
    // NWG = 276; bijective chunked swizzle: q=34, r=4
    int d = blockIdx.x;
    int xcd = d & 7;
    int posn = d >> 3;
    int base = (xcd < 4) ? xcd * 35 : 140 + (xcd - 4) * 34;
    int w = base + posn;
    int bx = w & (GX - 1);
    int ti = w >> 2;
    int e = meta[16 + ti];
    if (e < 0) return;

    int base_p = meta[5 + e];
    int cnt = meta[e];
    int m0 = ti * 128 - base_p;
    int n0 = bx * 256;

    __shared__ __align__(16) bf16 As[3][128 * 32];   // 24 KB
    __shared__ __align__(16) bf16 Bs[3][256 * 32];   // 48 KB

    int t = threadIdx.x;
    int lane = t & 63;
    int wv = t >> 6;
    int wr = wv >> 1, wcol = wv & 1;

    int i0 = (t & 7) ^ ((t >> 3) & 7);
    int srow = 2 * (t >> 3) + (i0 >> 2);
    int schk = i0 & 3;

    int r1 = min(m0 + srow, cnt - 1);
    int r2 = min(m0 + 64 + srow, cnt - 1);
    const bf16* ga1 = ks + (size_t)(base_p + r1) * H_DIM + schk * 8;
    const bf16* ga2 = ks + (size_t)(base_p + r2) * H_DIM + schk * 8;
    const bf16* wbase = w2t + (size_t)e * C_DIM * H_DIM;
    const bf16* gb[4];
#pragma unroll
    for (int h = 0; h < 4; ++h)
        gb[h] = wbase + (size_t)(n0 + h * 64 + srow) * H_DIM + schk * 8;

    int lo1 = t * 8;            // linear LDS offset within a 64-row half (2048 elems)
    int lo2 = 2048 + t * 8;

    int kq = lane >> 4;
    int rhalf = (lane & 15) >> 1;
    int ifrag = ((lane & 1) << 2) | kq;
    int foff = rhalf * 64 + (ifrag ^ rhalf) * 8;
    int aoff = wr * 2048 + foff;       // wave's 64-row half of A
    int boff = wcol * 4096 + foff;     // wave's 128-col (2-half) span of B

    f4v acc[4][8];
    f4v zero = {0.f, 0.f, 0.f, 0.f};
#pragma unroll
    for (int i = 0; i < 4; ++i)
#pragma unroll
        for (int j = 0; j < 8; ++j) acc[i][j] = zero;

    const int nk = H_DIM / 32;  // 128

    // prologue: stage tiles 0,1 into slots 0,1 (12 loads in flight)
#pragma unroll
    for (int pt = 0; pt < 2; ++pt) {
        async_ld16(ga1, &As[pt][lo1]); ga1 += 32;
        async_ld16(ga2, &As[pt][lo2]); ga2 += 32;
#pragma unroll
        for (int h = 0; h < 4; ++h) {
            async_ld16(gb[h], &Bs[pt][h * 2048 + t * 8]); gb[h] += 32;
        }
    }

    int cur = 0, st = 2;
    for (int kb = 0; kb < nk; ++kb) {
        if (kb < nk - 2) {
            async_ld16(ga1, &As[st][lo1]); ga1 += 32;
            async_ld16(ga2, &As[st][lo2]); ga2 += 32;
#pragma unroll
            for (int h = 0; h < 4; ++h) {
                async_ld16(gb[h], &Bs[st][h * 2048 + t * 8]); gb[h] += 32;
            }
            asm volatile("s_waitcnt vmcnt(12)" ::: "memory");  // tile kb landed
        } else if (kb == nk - 2) {
            asm volatile("s_waitcnt vmcnt(6)" ::: "memory");
        } else {
            asm volatile("s_waitcnt vmcnt(0)" ::: "memory");
        }
        __builtin_amdgcn_s_barrier();                          // tile kb ready

        const bf16* Ac = &As[cur][0];
        const bf16* Bc = &Bs[cur][0];
        s8v af[4], bfv[8];
#pragma unroll
        for (int mi = 0; mi < 4; ++mi)
            af[mi] = *(const s8v*)(Ac + aoff + mi * 512);
#pragma unroll
        for (int ni = 0; ni < 8; ++ni)
            bfv[ni] = *(const s8v*)(Bc + boff + ni * 512);
#pragma unroll
        for (int mi = 0; mi < 4; ++mi)
#pragma unroll
            for (int ni = 0; ni < 8; ++ni)
                acc[mi][ni] = __builtin_amdgcn_mfma_f32_16x16x32_bf16(af[mi], bfv[ni], acc[mi][ni], 0, 0, 0);

        asm volatile("s_waitcnt lgkmcnt(0)" ::: "memory");     // my slot-cur reads done
        __builtin_amdgcn_s_barrier();                          // slot cur free
        cur = (cur == 2) ? 0 : cur + 1;
        st  = (st  == 2) ? 0 : st  + 1;
    }

#pragma unroll
    for (int mi = 0; mi < 4; ++mi) {
        int tok[4];
        float sclv[4];
#pragma unroll
        for (int r = 0; r < 4; ++r) {
            int row_local = wr * 64 + mi * 16 + ((lane >> 4) << 2) + r;
            int gm = m0 + row_local;
            if (gm < cnt) {
                tok[r] = idx[base_p + gm];
                sclv[r] = scl[base_p + gm];
            } else {
                tok[r] = -1;
                sclv[r] = 0.f;
            }
        }
#pragma unroll
        for (int ni = 0; ni < 8; ++ni) {
            int col = n0 + wcol * 128 + ni * 16 + (lane & 15);
#pragma unroll
            for (int r = 0; r < 4; ++r) {
                if (tok[r] >= 0) {
                    size_t o = (size_t)tok[r] * C_DIM + col;
                    out[o] = x[o] + acc[mi][ni][r] * sclv[r];
                }
            }
        }
    }
}

extern "C" void kernel_launch(void* const* d_in, const int* in_sizes, int n_in,
                              void* d_out, int out_size, void* d_ws, size_t ws_size,
                              hipStream_t stream) {
    const float* x     = (const float*)d_in[0];
    const int*   win   = (const int*)d_in[1];
    const float* gamma = (const float*)d_in[2];
    const float* beta  = (const float*)d_in[3];
    const float* w1    = (const float*)d_in[4];
    const float* w2    = (const float*)d_in[5];
    const float* wc    = (const float*)d_in[6];
    const float* bc    = (const float*)d_in[7];
    float* out = (float*)d_out;

    char* ws = (char*)d_ws;
    size_t o = 0;
    bf16* w1t  = (bf16*)(ws + o); o += (size_t)E_NUM * H_DIM * C_DIM * 2;  // 40 MB
    bf16* w2t  = (bf16*)(ws + o); o += (size_t)E_NUM * C_DIM * H_DIM * 2;  // 40 MB
    bf16* hbuf = (bf16*)(ws + o); o += (size_t)N_PAD * C_DIM * 2;          // 17 MB
    bf16* ks   = (bf16*)(ws + o); o += (size_t)N_PAD * H_DIM * 2;          // 69 MB
    float* scl = (float*)(ws + o); o += (size_t)N_PAD * 4;
    int* idx   = (int*)(ws + o);   o += (size_t)N_PAD * 4;
    int* pos   = (int*)(ws + o);   o += (size_t)N_TOK * 4;
    int* meta  = (int*)(ws + o);   o += 512;

    hipLaunchKernelGGL(count_scan_kernel, dim3(1), dim3(1024), 0, stream, win, meta);
    hipLaunchKernelGGL(scatter_kernel, dim3(N_TOK / 256), dim3(256), 0, stream, win, meta, idx, pos);
    hipLaunchKernelGGL(ln_conf_w1t_kernel, dim3(N_TOK + 5120), dim3(256), 0, stream,
                       x, win, gamma, beta, wc, bc, pos, hbuf, scl, w1, w1t);
    hipLaunchKernelGGL(gemm1_w2t_kernel, dim3(2208 + 5120), dim3(256), 0, stream,
                       hbuf, w1t, meta, ks, w2, w2t);
    hipLaunchKernelGGL(gemm2_kernel, dim3(276), dim3(256), 0, stream,
                       ks, w2t, idx, meta, x, scl, out);
}

// Round 15
// 437.291 us; speedup vs baseline: 1.4270x; 1.4270x over previous
//
#include <hip/hip_runtime.h>
#include <hip/hip_bf16.h>
#include <stdint.h>

#define N_TOK 8192
#define C_DIM 1024
#define H_DIM 4096
#define E_NUM 5
#define LN_EPS 1e-5f
#define NT_MAX 69              // ceil((8192 + 5*127)/128): padded 128-row M-tiles
#define N_PAD (NT_MAX * 128)   // 8832 padded sorted rows

typedef __hip_bfloat16 bf16;
using s8v = __attribute__((ext_vector_type(8))) short;
using f4v = __attribute__((ext_vector_type(4))) float;

// async global->LDS, 16B per lane. LDS dest must be linear: wave-uniform base + lane*16.
__device__ __forceinline__ void async_ld16(const bf16* g, bf16* l) {
    __builtin_amdgcn_global_load_lds(
        (const __attribute__((address_space(1))) void*)g,
        (__attribute__((address_space(3))) void*)l,
        16, 0, 0);
}

// meta layout (ints): [0..4]=counts, [5..9]=128-aligned offsets, [10]=padded total,
// [11..15]=cursors, [16..16+NT_MAX)=tile->expert table (-1 = empty tile)

// Fused count+scan: one block, LDS histogram, then meta build.
// (R12 lesson: do NOT also fuse scatter — serializing 8192 tokens' ranking
// through one CU costs more than the launch boundary it saves.)
__global__ __launch_bounds__(1024) void count_scan_kernel(
    const int* __restrict__ win, int* __restrict__ meta)
{
    __shared__ int c[E_NUM];
    int t = threadIdx.x;
    if (t < E_NUM) c[t] = 0;
    __syncthreads();
    for (int n = t; n < N_TOK; n += 1024) atomicAdd(&c[win[n]], 1);
    __syncthreads();
    if (t == 0) {
        int off = 0;
        for (int e = 0; e < E_NUM; ++e) {
            meta[e] = c[e];
            meta[5 + e] = off;
            off += (c[e] + 127) & ~127;        // 128-aligned segment
            meta[11 + e] = 0;                  // scatter cursor
        }
        meta[10] = off;
        int ti = 0;
        for (int e = 0; e < E_NUM; ++e) {
            int tiles = (c[e] + 127) >> 7;
            for (int j = 0; j < tiles; ++j) meta[16 + ti++] = e;
        }
        for (; ti < NT_MAX; ++ti) meta[16 + ti] = -1;
    }
}

// Hierarchical scatter (R10 lesson: per-token device-scope atomics on one
// cache line serialize at ~60ns each = 490 µs; LDS local ranks + E_NUM global
// atomics per block = 160 total is ~2 µs).
__global__ __launch_bounds__(256) void scatter_kernel(
    const int* __restrict__ win, int* __restrict__ meta,
    int* __restrict__ idx, int* __restrict__ pos)
{
    __shared__ int c[E_NUM];
    __shared__ int base[E_NUM];
    if (threadIdx.x < E_NUM) c[threadIdx.x] = 0;
    __syncthreads();
    int n = blockIdx.x * 256 + threadIdx.x;
    int e = win[n];
    int lr = atomicAdd(&c[e], 1);
    __syncthreads();
    if (threadIdx.x < E_NUM)
        base[threadIdx.x] = atomicAdd(&meta[11 + threadIdx.x], c[threadIdx.x]);
    __syncthreads();
    int p = meta[5 + e] + base[e] + lr;
    idx[p] = n;
    pos[n] = p;
}

// Shared transpose tile body: src [R][S] fp32 (+ebase) -> dst [S][R] bf16.
// 64x64 tile at (r0, s0); float4 loads; 8 lanes x 16B = one 128B dst line.
__device__ __forceinline__ void transpose_tile(
    const float* __restrict__ src, bf16* __restrict__ dst,
    size_t ebase, int R, int S, int r0, int s0, float (*tile)[65])
{
    int t = threadIdx.x;
    int lr = t >> 4;
    int lc = (t & 15) * 4;
#pragma unroll
    for (int i = 0; i < 4; ++i) {
        int rr = lr + i * 16;
        float4 v = *(const float4*)(src + ebase + (size_t)(r0 + rr) * S + s0 + lc);
        tile[rr][lc + 0] = v.x;
        tile[rr][lc + 1] = v.y;
        tile[rr][lc + 2] = v.z;
        tile[rr][lc + 3] = v.w;
    }
    __syncthreads();
    int ch = t & 7;
    int scb = t >> 3;
#pragma unroll
    for (int p = 0; p < 2; ++p) {
        int sc = scb + p * 32;
        bf16 vals[8];
#pragma unroll
        for (int j = 0; j < 8; ++j)
            vals[j] = (bf16)tile[ch * 8 + j][sc];
        *(s8v*)(dst + ebase + (size_t)(s0 + sc) * R + r0 + ch * 8) = *(s8v*)vals;
    }
}

// Fused: ln_conf (blocks 0..8191) + w1 transpose (blocks 8192..13311).
// Independent work; both finish before gemm1 (stream order).
__global__ __launch_bounds__(256) void ln_conf_w1t_kernel(
    const float* __restrict__ x, const int* __restrict__ win,
    const float* __restrict__ gamma, const float* __restrict__ beta,
    const float* __restrict__ wc, const float* __restrict__ bc,
    const int* __restrict__ pos,
    bf16* __restrict__ hbuf, float* __restrict__ scl,
    const float* __restrict__ w1, bf16* __restrict__ w1t)
{
    __shared__ float tile[64][65];
    if (blockIdx.x >= N_TOK) {
        int r = blockIdx.x - N_TOK;            // [0, 5120)
        int e = r >> 10;
        int cell = r & 1023;
        transpose_tile(w1, w1t, (size_t)e * C_DIM * H_DIM, C_DIM, H_DIM,
                       (cell >> 6) * 64, (cell & 63) * 64, tile);
        return;
    }
    int n = blockIdx.x;
    int t = threadIdx.x;
    const float* xr = x + (size_t)n * C_DIM;
    float v[4];
    float s = 0.f, ss = 0.f;
#pragma unroll
    for (int i = 0; i < 4; ++i) {
        v[i] = xr[t + i * 256];
        s += v[i];
        ss += v[i] * v[i];
    }
#pragma unroll
    for (int off = 32; off > 0; off >>= 1) {
        s  += __shfl_down(s, off);
        ss += __shfl_down(ss, off);
    }
    __shared__ float red[8];
    __shared__ float mu_s, rv_s;
    int wave = t >> 6, lane = t & 63;
    if (lane == 0) { red[wave] = s; red[4 + wave] = ss; }
    __syncthreads();
    if (t == 0) {
        float S  = red[0] + red[1] + red[2] + red[3];
        float SS = red[4] + red[5] + red[6] + red[7];
        float mu = S * (1.f / C_DIM);
        float var = SS * (1.f / C_DIM) - mu * mu;
        mu_s = mu;
        rv_s = rsqrtf(var + LN_EPS);
    }
    __syncthreads();
    float mu = mu_s, rv = rv_s;
    int e = win[n];
    int p = pos[n];
    const float* wce = wc + (size_t)e * C_DIM;
    float dot = 0.f;
#pragma unroll
    for (int i = 0; i < 4; ++i) {
        int ci = t + i * 256;
        float hv = (v[i] - mu) * rv * gamma[ci] + beta[ci];
        hbuf[(size_t)p * C_DIM + ci] = (bf16)hv;
        dot += hv * wce[ci];
    }
#pragma unroll
    for (int off = 32; off > 0; off >>= 1) dot += __shfl_down(dot, off);
    if (lane == 0) red[wave] = dot;
    __syncthreads();
    if (t == 0) {
        float z = red[0] + red[1] + red[2] + red[3] + bc[e];
        float conf = 1.f / (1.f + expf(-z));
        scl[p] = conf / (conf + 1e-6f);
    }
}

// ---------------- GEMM cores (R7 = validated config) -------------------------
// 1-D XCD-chunked swizzle w = (d&7)*(NWG/8) + d>>3, bx-fastest inner order:
// temporal A-reuse keeps FETCH at the compulsory minimum (R8 lesson: 2-D
// rectangles spread A readers in time -> L3 evictions -> +71 MB HBM re-reads).
// Conflict-free LDS swizzle (R2-validated: conflicts 8.65M -> 0).
// R14 lesson: concurrency floor is ~2 blocks/CU — BN=256 (276 blocks,
// 1.08/CU) collapsed to MfmaUtil 8.7%. 128x128/552-block gemm2 is the
// unique config satisfying both minimum traffic AND the TLP floor.

// Fused: gemm1 (blocks 0..2207) + w2 transpose (blocks 2208..7327).
// w2t is only read by gemm2 (next launch); transpose blocks backfill CUs as
// gemm1 blocks retire and use gemm1's idle HBM bandwidth. (R11 refuted the
// tail-pollution hypothesis: gemm2's 127-147 µs spread is chip variance.)
__global__ __launch_bounds__(256) void gemm1_w2t_kernel(
    const bf16* __restrict__ hbuf, const bf16* __restrict__ w1t,
    const int* __restrict__ meta, bf16* __restrict__ ks,
    const float* __restrict__ w2, bf16* __restrict__ w2t)
{
    const int GX = H_DIM / 128;            // 32
    const int NWG = GX * NT_MAX;           // 2208 (% 8 == 0)
    if (blockIdx.x >= NWG) {
        __shared__ float tile[64][65];
        int r = blockIdx.x - NWG;              // [0, 5120)
        int e = r >> 10;
        int cell = r & 1023;
        transpose_tile(w2, w2t, (size_t)e * H_DIM * C_DIM, H_DIM, C_DIM,
                       (cell >> 4) * 64, (cell & 15) * 64, tile);
        return;
    }
    int d = blockIdx.x;
    int w = (d & 7) * (NWG >> 3) + (d >> 3);
    int bx = w & (GX - 1);
    int ti = w / GX;
    int e = meta[16 + ti];
    if (e < 0) return;

    int base_p = meta[5 + e];
    int cnt = meta[e];
    int m0 = ti * 128 - base_p;            // local row within expert segment
    int n0 = bx * 128;

    __shared__ __align__(16) bf16 As[128 * 32];
    __shared__ __align__(16) bf16 Bs[128 * 32];

    int t = threadIdx.x;
    int lane = t & 63;
    int wv = t >> 6;
    int wr = wv >> 1, wcol = wv & 1;

    int i0 = (t & 7) ^ ((t >> 3) & 7);
    int srow = 2 * (t >> 3) + (i0 >> 2);
    int schk = i0 & 3;

    int r1 = min(m0 + srow, cnt - 1);
    int r2 = min(m0 + 64 + srow, cnt - 1);
    const bf16* ga1 = hbuf + (size_t)(base_p + r1) * C_DIM + schk * 8;
    const bf16* ga2 = hbuf + (size_t)(base_p + r2) * C_DIM + schk * 8;
    const bf16* wbase = w1t + (size_t)e * H_DIM * C_DIM;
    const bf16* gb1 = wbase + (size_t)(n0 + srow) * C_DIM + schk * 8;
    const bf16* gb2 = wbase + (size_t)(n0 + 64 + srow) * C_DIM + schk * 8;

    bf16* la1 = As + t * 8;
    bf16* la2 = As + 2048 + t * 8;
    bf16* lb1 = Bs + t * 8;
    bf16* lb2 = Bs + 2048 + t * 8;

    int kq = lane >> 4;
    int rhalf = (lane & 15) >> 1;
    int ifrag = ((lane & 1) << 2) | kq;
    int foff = rhalf * 64 + (ifrag ^ rhalf) * 8;
    const bf16* Af = As + wr * 2048 + foff;
    const bf16* Bf = Bs + wcol * 2048 + foff;

    f4v acc[4][4];
    f4v zero = {0.f, 0.f, 0.f, 0.f};
#pragma unroll
    for (int i = 0; i < 4; ++i)
#pragma unroll
        for (int j = 0; j < 4; ++j) acc[i][j] = zero;

    for (int kb = 0; kb < C_DIM / 32; ++kb) {
        __syncthreads();
        async_ld16(ga1, la1); ga1 += 32;
        async_ld16(ga2, la2); ga2 += 32;
        async_ld16(gb1, lb1); gb1 += 32;
        async_ld16(gb2, lb2); gb2 += 32;
        __syncthreads();
        s8v af[4], bfv[4];
#pragma unroll
        for (int mi = 0; mi < 4; ++mi)
            af[mi] = *(const s8v*)(Af + mi * 512);
#pragma unroll
        for (int ni = 0; ni < 4; ++ni)
            bfv[ni] = *(const s8v*)(Bf + ni * 512);
#pragma unroll
        for (int mi = 0; mi < 4; ++mi)
#pragma unroll
            for (int ni = 0; ni < 4; ++ni)
                acc[mi][ni] = __builtin_amdgcn_mfma_f32_16x16x32_bf16(af[mi], bfv[ni], acc[mi][ni], 0, 0, 0);
    }

#pragma unroll
    for (int mi = 0; mi < 4; ++mi) {
#pragma unroll
        for (int r = 0; r < 4; ++r) {
            int row_local = wr * 64 + mi * 16 + ((lane >> 4) << 2) + r;
            int gm = m0 + row_local;
            if (gm < cnt) {
                size_t p = (size_t)(base_p + gm);
#pragma unroll
                for (int ni = 0; ni < 4; ++ni) {
                    int col = n0 + wcol * 64 + ni * 16 + (lane & 15);
                    float v = acc[mi][ni][r];
                    float rl = fmaxf(v, 0.f);
                    ks[p * H_DIM + col] = (bf16)(rl * rl);
                }
            }
        }
    }
}

// Stage 2: out[tok] = x[tok] + (ks[p] @ W2t[e][c])*scl[p]
// 3-slot depth-2 counted-vmcnt ring at 48KB (validated R5/R7): all 552 blocks
// co-resident (R6 lesson: 64KB caps 2/CU and serializes a 40-block tail).
__global__ __launch_bounds__(256) void gemm2_kernel(
    const bf16* __restrict__ ks, const bf16* __restrict__ w2t,
    const int* __restrict__ idx, const int* __restrict__ meta,
    const float* __restrict__ x, const float* __restrict__ scl,
    float* __restrict__ out)
{
    const int GX = C_DIM / 128;            // 8
    const int NWG = GX * NT_MAX;           // 552 (% 8 == 0)
    int d = blockIdx.y * GX + blockIdx.x;
    int w = (d & 7) * (NWG >> 3) + (d >> 3);
    int bx = w & (GX - 1);
    int ti = w / GX;
    int e = meta[16 + ti];
    if (e < 0) return;

    int base_p = meta[5 + e];
    int cnt = meta[e];
    int m0 = ti * 128 - base_p;
    int n0 = bx * 128;

    __shared__ __align__(16) bf16 As[3][128 * 32];
    __shared__ __align__(16) bf16 Bs[3][128 * 32];

    int t = threadIdx.x;
    int lane = t & 63;
    int wv = t >> 6;
    int wr = wv >> 1, wcol = wv & 1;

    int i0 = (t & 7) ^ ((t >> 3) & 7);
    int srow = 2 * (t >> 3) + (i0 >> 2);
    int schk = i0 & 3;

    int r1 = min(m0 + srow, cnt - 1);
    int r2 = min(m0 + 64 + srow, cnt - 1);
    const bf16* ga1 = ks + (size_t)(base_p + r1) * H_DIM + schk * 8;
    const bf16* ga2 = ks + (size_t)(base_p + r2) * H_DIM + schk * 8;
    const bf16* wbase = w2t + (size_t)e * C_DIM * H_DIM;
    const bf16* gb1 = wbase + (size_t)(n0 + srow) * H_DIM + schk * 8;
    const bf16* gb2 = wbase + (size_t)(n0 + 64 + srow) * H_DIM + schk * 8;

    int lo1 = t * 8;
    int lo2 = 2048 + t * 8;

    int kq = lane >> 4;
    int rhalf = (lane & 15) >> 1;
    int ifrag = ((lane & 1) << 2) | kq;
    int foff = rhalf * 64 + (ifrag ^ rhalf) * 8;
    int aoff = wr * 2048 + foff;
    int boff = wcol * 2048 + foff;

    f4v acc[4][4];
    f4v zero = {0.f, 0.f, 0.f, 0.f};
#pragma unroll
    for (int i = 0; i < 4; ++i)
#pragma unroll
        for (int j = 0; j < 4; ++j) acc[i][j] = zero;

    const int nk = H_DIM / 32;  // 128

#pragma unroll
    for (int pt = 0; pt < 2; ++pt) {
        async_ld16(ga1, &As[pt][lo1]); ga1 += 32;
        async_ld16(ga2, &As[pt][lo2]); ga2 += 32;
        async_ld16(gb1, &Bs[pt][lo1]); gb1 += 32;
        async_ld16(gb2, &Bs[pt][lo2]); gb2 += 32;
    }

    int cur = 0, st = 2;
    for (int kb = 0; kb < nk; ++kb) {
        if (kb < nk - 2) {
            async_ld16(ga1, &As[st][lo1]); ga1 += 32;
            async_ld16(ga2, &As[st][lo2]); ga2 += 32;
            async_ld16(gb1, &Bs[st][lo1]); gb1 += 32;
            async_ld16(gb2, &Bs[st][lo2]); gb2 += 32;
            asm volatile("s_waitcnt vmcnt(8)" ::: "memory");   // tile kb landed
        } else if (kb == nk - 2) {
            asm volatile("s_waitcnt vmcnt(4)" ::: "memory");
        } else {
            asm volatile("s_waitcnt vmcnt(0)" ::: "memory");
        }
        __builtin_amdgcn_s_barrier();                          // tile kb ready

        const bf16* Ac = &As[cur][0];
        const bf16* Bc = &Bs[cur][0];
        s8v af[4], bfv[4];
#pragma unroll
        for (int mi = 0; mi < 4; ++mi)
            af[mi] = *(const s8v*)(Ac + aoff + mi * 512);
#pragma unroll
        for (int ni = 0; ni < 4; ++ni)
            bfv[ni] = *(const s8v*)(Bc + boff + ni * 512);
#pragma unroll
        for (int mi = 0; mi < 4; ++mi)
#pragma unroll
            for (int ni = 0; ni < 4; ++ni)
                acc[mi][ni] = __builtin_amdgcn_mfma_f32_16x16x32_bf16(af[mi], bfv[ni], acc[mi][ni], 0, 0, 0);

        asm volatile("s_waitcnt lgkmcnt(0)" ::: "memory");     // my slot-cur reads done
        __builtin_amdgcn_s_barrier();                          // slot cur free
        cur = (cur == 2) ? 0 : cur + 1;
        st  = (st  == 2) ? 0 : st  + 1;
    }

#pragma unroll
    for (int mi = 0; mi < 4; ++mi) {
        int tok[4];
        float sclv[4];
#pragma unroll
        for (int r = 0; r < 4; ++r) {
            int row_local = wr * 64 + mi * 16 + ((lane >> 4) << 2) + r;
            int gm = m0 + row_local;
            if (gm < cnt) {
                tok[r] = idx[base_p + gm];
                sclv[r] = scl[base_p + gm];
            } else {
                tok[r] = -1;
                sclv[r] = 0.f;
            }
        }
#pragma unroll
        for (int ni = 0; ni < 4; ++ni) {
            int col = n0 + wcol * 64 + ni * 16 + (lane & 15);
#pragma unroll
            for (int r = 0; r < 4; ++r) {
                if (tok[r] >= 0) {
                    size_t o = (size_t)tok[r] * C_DIM + col;
                    out[o] = x[o] + acc[mi][ni][r] * sclv[r];
                }
            }
        }
    }
}

extern "C" void kernel_launch(void* const* d_in, const int* in_sizes, int n_in,
                              void* d_out, int out_size, void* d_ws, size_t ws_size,
                              hipStream_t stream) {
    const float* x     = (const float*)d_in[0];
    const int*   win   = (const int*)d_in[1];
    const float* gamma = (const float*)d_in[2];
    const float* beta  = (const float*)d_in[3];
    const float* w1    = (const float*)d_in[4];
    const float* w2    = (const float*)d_in[5];
    const float* wc    = (const float*)d_in[6];
    const float* bc    = (const float*)d_in[7];
    float* out = (float*)d_out;

    char* ws = (char*)d_ws;
    size_t o = 0;
    bf16* w1t  = (bf16*)(ws + o); o += (size_t)E_NUM * H_DIM * C_DIM * 2;  // 40 MB
    bf16* w2t  = (bf16*)(ws + o); o += (size_t)E_NUM * C_DIM * H_DIM * 2;  // 40 MB
    bf16* hbuf = (bf16*)(ws + o); o += (size_t)N_PAD * C_DIM * 2;          // 17 MB
    bf16* ks   = (bf16*)(ws + o); o += (size_t)N_PAD * H_DIM * 2;          // 69 MB
    float* scl = (float*)(ws + o); o += (size_t)N_PAD * 4;
    int* idx   = (int*)(ws + o);   o += (size_t)N_PAD * 4;
    int* pos   = (int*)(ws + o);   o += (size_t)N_TOK * 4;
    int* meta  = (int*)(ws + o);   o += 512;

    hipLaunchKernelGGL(count_scan_kernel, dim3(1), dim3(1024), 0, stream, win, meta);
    hipLaunchKernelGGL(scatter_kernel, dim3(N_TOK / 256), dim3(256), 0, stream, win, meta, idx, pos);
    hipLaunchKernelGGL(ln_conf_w1t_kernel, dim3(N_TOK + 5120), dim3(256), 0, stream,
                       x, win, gamma, beta, wc, bc, pos, hbuf, scl, w1, w1t);
    hipLaunchKernelGGL(gemm1_w2t_kernel, dim3(2208 + 5120), dim3(256), 0, stream,
                       hbuf, w1t, meta, ks, w2, w2t);
    hipLaunchKernelGGL(gemm2_kernel, dim3(C_DIM / 128, NT_MAX), dim3(256), 0, stream,
                       ks, w2t, idx, meta, x, scl, out);
}